// Round 1
// baseline (285.657 us; speedup 1.0000x reference)
//
#include <hip/hip_runtime.h>
#include <math.h>

// Problem shape (fixed by reference setup_inputs):
//   B=32, H=64, W=64, C=256, NHWC layout (C contiguous).
//   Outputs: x (B,H,W,C) fp32 then gate (B,1,1,C) fp32, concatenated flat.
#define B_ 32
#define HW_ 4096          // 64*64
#define C_ 256
#define C4_ 64            // C/4
#define NCHUNK 32         // spatial chunks per batch in pass 1
#define CHUNK 128         // HW_/NCHUNK positions per chunk

// ---------------- Kernel 1: partial spatial sum/max reduction ----------------
// Grid: B*NCHUNK blocks, 256 threads. Thread layout: t = pg*64 + c4,
// pg in [0,4) position-group, c4 in [0,64) float4 channel group.
// Each thread strides positions by 4, float4 over channels (16B/lane).
__global__ __launch_bounds__(256) void pool_partial_kernel(
    const float* __restrict__ in, float* __restrict__ ws_sum,
    float* __restrict__ ws_max) {
  const int b = blockIdx.x >> 5;   // / NCHUNK
  const int k = blockIdx.x & 31;   // % NCHUNK
  const int t = threadIdx.x;
  const int c4 = t & 63;
  const int pg = t >> 6;           // 0..3

  const float4* in4 = (const float4*)in;
  // float4 index of (b, pos = k*CHUNK + pg, channel-group c4)
  long base = (long)b * (HW_ * C4_) + (long)(k * CHUNK + pg) * C4_ + c4;

  float4 s = make_float4(0.f, 0.f, 0.f, 0.f);
  float4 m = make_float4(-INFINITY, -INFINITY, -INFINITY, -INFINITY);
#pragma unroll 4
  for (int p = 0; p < CHUNK; p += 4) {
    float4 v = in4[base + (long)p * C4_];
    s.x += v.x; s.y += v.y; s.z += v.z; s.w += v.w;
    m.x = fmaxf(m.x, v.x); m.y = fmaxf(m.y, v.y);
    m.z = fmaxf(m.z, v.z); m.w = fmaxf(m.w, v.w);
  }

  __shared__ float4 ssum[256];
  __shared__ float4 smax[256];
  ssum[t] = s;
  smax[t] = m;
  __syncthreads();

  if (pg == 0) {
#pragma unroll
    for (int q = 1; q < 4; ++q) {
      float4 s2 = ssum[q * 64 + c4];
      float4 m2 = smax[q * 64 + c4];
      s.x += s2.x; s.y += s2.y; s.z += s2.z; s.w += s2.w;
      m.x = fmaxf(m.x, m2.x); m.y = fmaxf(m.y, m2.y);
      m.z = fmaxf(m.z, m2.z); m.w = fmaxf(m.w, m2.w);
    }
    float4* wsum4 = (float4*)ws_sum;
    float4* wmax4 = (float4*)ws_max;
    wsum4[(b * NCHUNK + k) * C4_ + c4] = s;
    wmax4[(b * NCHUNK + k) * C4_ + c4] = m;
  }
}

// ---------------- Kernel 2: finish reduction + GEMM + BN + gate ----------------
// Grid: B blocks, 256 threads (one per channel).
__global__ __launch_bounds__(256) void gate_kernel(
    const float* __restrict__ ws_sum, const float* __restrict__ ws_max,
    const float* __restrict__ factor, const float* __restrict__ W1,
    const float* __restrict__ b1, const float* __restrict__ gamma,
    const float* __restrict__ beta, const float* __restrict__ bn_mean,
    const float* __restrict__ bn_var, const float* __restrict__ Wg,
    const float* __restrict__ bg, const float* __restrict__ gumbel,
    float* __restrict__ ws_gate, float* __restrict__ out_gate) {
  const int b = blockIdx.x;
  const int j = threadIdx.x;  // channel

  float s = 0.f;
  float m = -INFINITY;
#pragma unroll 8
  for (int k = 0; k < NCHUNK; ++k) {
    s += ws_sum[(b * NCHUNK + k) * C_ + j];
    m = fmaxf(m, ws_max[(b * NCHUNK + k) * C_ + j]);
  }

  // softmax over the 2 blend factors
  float a0 = factor[0], a1 = factor[1];
  float mx = fmaxf(a0, a1);
  float e0 = expf(a0 - mx), e1 = expf(a1 - mx);
  float inv = 1.f / (e0 + e1);
  float f0 = e0 * inv, f1 = e1 * inv;

  __shared__ float pool[C_];
  pool[j] = (s * (1.0f / (float)HW_)) * f0 + m * f1;
  __syncthreads();

  // h[j] = sum_c pool[c] * W1[c,j] + b1[j]
  float h = b1[j];
#pragma unroll 8
  for (int c = 0; c < C_; ++c) {
    h = fmaf(pool[c], W1[c * C_ + j], h);
  }
  // BatchNorm (inference) + ReLU
  h = gamma[j] * (h - bn_mean[j]) * rsqrtf(bn_var[j] + 1e-3f) + beta[j];
  h = fmaxf(h, 0.f);

  // grouped 1x1 conv -> 2 logits, + gumbel; hard sample = argmax
  float z0 = fmaf(h, Wg[j * 2 + 0], bg[j * 2 + 0]) + gumbel[(b * C_ + j) * 2 + 0];
  float z1 = fmaf(h, Wg[j * 2 + 1], bg[j * 2 + 1]) + gumbel[(b * C_ + j) * 2 + 1];
  // argmax picks index 0 on ties -> gate = 1 iff z1 > z0 strictly
  float g = (z1 > z0) ? 1.0f : 0.0f;

  ws_gate[b * C_ + j] = g;
  out_gate[b * C_ + j] = g;
}

// ---------------- Kernel 3: x = inputs * gate[b,c] ----------------
// One float4 per thread; 2^23 float4s total.
__global__ __launch_bounds__(256) void apply_gate_kernel(
    const float* __restrict__ in, const float* __restrict__ ws_gate,
    float* __restrict__ out) {
  long i = (long)blockIdx.x * blockDim.x + threadIdx.x;  // float4 index
  const float4* in4 = (const float4*)in;
  const float4* g4 = (const float4*)ws_gate;
  float4* out4 = (float4*)out;

  int b = (int)(i >> 18);   // HW_*C4_ = 4096*64 = 2^18 float4s per batch
  int c4 = (int)(i & 63);   // C4_ - 1

  float4 g = g4[b * C4_ + c4];
  float4 v = in4[i];
  v.x *= g.x; v.y *= g.y; v.z *= g.z; v.w *= g.w;
  out4[i] = v;
}

extern "C" void kernel_launch(void* const* d_in, const int* in_sizes, int n_in,
                              void* d_out, int out_size, void* d_ws, size_t ws_size,
                              hipStream_t stream) {
  const float* inputs  = (const float*)d_in[0];
  const float* factor  = (const float*)d_in[1];
  const float* W1      = (const float*)d_in[2];
  const float* b1      = (const float*)d_in[3];
  const float* gamma   = (const float*)d_in[4];
  const float* beta    = (const float*)d_in[5];
  const float* bn_mean = (const float*)d_in[6];
  const float* bn_var  = (const float*)d_in[7];
  const float* Wg      = (const float*)d_in[8];
  const float* bg      = (const float*)d_in[9];
  const float* gumbel  = (const float*)d_in[10];

  float* out_x = (float*)d_out;                          // B*H*W*C floats
  float* out_gate = (float*)d_out + (long)B_ * HW_ * C_; // B*C floats

  // Workspace layout (floats):
  float* ws_sum  = (float*)d_ws;                   // B*NCHUNK*C = 262144
  float* ws_max  = ws_sum + B_ * NCHUNK * C_;      // 262144
  float* ws_gate = ws_max + B_ * NCHUNK * C_;      // B*C = 8192

  pool_partial_kernel<<<B_ * NCHUNK, 256, 0, stream>>>(inputs, ws_sum, ws_max);

  gate_kernel<<<B_, 256, 0, stream>>>(ws_sum, ws_max, factor, W1, b1, gamma,
                                      beta, bn_mean, bn_var, Wg, bg, gumbel,
                                      ws_gate, out_gate);

  const long n4 = (long)B_ * HW_ * C4_;  // 2^23 float4s
  apply_gate_kernel<<<(int)(n4 / 256), 256, 0, stream>>>(inputs, ws_gate, out_x);
}

// Round 3
// 276.775 us; speedup vs baseline: 1.0321x; 1.0321x over previous
//
#include <hip/hip_runtime.h>
#include <math.h>

// Problem shape (fixed by reference setup_inputs):
//   B=32, H=64, W=64, C=256, NHWC layout (C contiguous).
//   Outputs: x (B,H,W,C) fp32 then gate (B,1,1,C) fp32, concatenated flat.
#define B_ 32
#define HW_ 4096          // 64*64
#define C_ 256
#define C4_ 64            // C/4
#define NCHUNK 32         // spatial chunks per batch in pass 1
#define CHUNK 128         // HW_/NCHUNK positions per chunk

// Native vector type — required for __builtin_nontemporal_store (HIP's
// float4 is a class and is rejected by the builtin).
typedef float vfloat4 __attribute__((ext_vector_type(4)));

// ---------------- Kernel 1: partial spatial sum/max reduction ----------------
// Grid: B*NCHUNK blocks, 256 threads. Thread layout: t = pg*64 + c4,
// pg in [0,4) position-group, c4 in [0,64) float4 channel group.
// Each thread strides positions by 4, float4 over channels (16B/lane).
__global__ __launch_bounds__(256) void pool_partial_kernel(
    const float* __restrict__ in, float* __restrict__ ws_sum,
    float* __restrict__ ws_max) {
  const int b = blockIdx.x >> 5;   // / NCHUNK
  const int k = blockIdx.x & 31;   // % NCHUNK
  const int t = threadIdx.x;
  const int c4 = t & 63;
  const int pg = t >> 6;           // 0..3

  const float4* in4 = (const float4*)in;
  // float4 index of (b, pos = k*CHUNK + pg, channel-group c4)
  long base = (long)b * (HW_ * C4_) + (long)(k * CHUNK + pg) * C4_ + c4;

  float4 s = make_float4(0.f, 0.f, 0.f, 0.f);
  float4 m = make_float4(-INFINITY, -INFINITY, -INFINITY, -INFINITY);
#pragma unroll 8
  for (int p = 0; p < CHUNK; p += 4) {
    float4 v = in4[base + (long)p * C4_];
    s.x += v.x; s.y += v.y; s.z += v.z; s.w += v.w;
    m.x = fmaxf(m.x, v.x); m.y = fmaxf(m.y, v.y);
    m.z = fmaxf(m.z, v.z); m.w = fmaxf(m.w, v.w);
  }

  __shared__ float4 ssum[256];
  __shared__ float4 smax[256];
  ssum[t] = s;
  smax[t] = m;
  __syncthreads();

  if (pg == 0) {
#pragma unroll
    for (int q = 1; q < 4; ++q) {
      float4 s2 = ssum[q * 64 + c4];
      float4 m2 = smax[q * 64 + c4];
      s.x += s2.x; s.y += s2.y; s.z += s2.z; s.w += s2.w;
      m.x = fmaxf(m.x, m2.x); m.y = fmaxf(m.y, m2.y);
      m.z = fmaxf(m.z, m2.z); m.w = fmaxf(m.w, m2.w);
    }
    float4* wsum4 = (float4*)ws_sum;
    float4* wmax4 = (float4*)ws_max;
    wsum4[(b * NCHUNK + k) * C4_ + c4] = s;
    wmax4[(b * NCHUNK + k) * C4_ + c4] = m;
  }
}

// ---------------- Kernel 2: finish reduction + GEMM + BN + gate ----------------
// Grid: B blocks, 256 threads (one per channel).
__global__ __launch_bounds__(256) void gate_kernel(
    const float* __restrict__ ws_sum, const float* __restrict__ ws_max,
    const float* __restrict__ factor, const float* __restrict__ W1,
    const float* __restrict__ b1, const float* __restrict__ gamma,
    const float* __restrict__ beta, const float* __restrict__ bn_mean,
    const float* __restrict__ bn_var, const float* __restrict__ Wg,
    const float* __restrict__ bg, const float* __restrict__ gumbel,
    float* __restrict__ ws_gate, float* __restrict__ out_gate) {
  const int b = blockIdx.x;
  const int j = threadIdx.x;  // channel

  float s = 0.f;
  float m = -INFINITY;
#pragma unroll 8
  for (int k = 0; k < NCHUNK; ++k) {
    s += ws_sum[(b * NCHUNK + k) * C_ + j];
    m = fmaxf(m, ws_max[(b * NCHUNK + k) * C_ + j]);
  }

  // softmax over the 2 blend factors
  float a0 = factor[0], a1 = factor[1];
  float mx = fmaxf(a0, a1);
  float e0 = expf(a0 - mx), e1 = expf(a1 - mx);
  float inv = 1.f / (e0 + e1);
  float f0 = e0 * inv, f1 = e1 * inv;

  __shared__ float pool[C_];
  pool[j] = (s * (1.0f / (float)HW_)) * f0 + m * f1;
  __syncthreads();

  // h[j] = sum_c pool[c] * W1[c,j] + b1[j]; 4 independent FMA chains for ILP
  float h0 = 0.f, h1 = 0.f, h2 = 0.f, h3 = 0.f;
#pragma unroll 8
  for (int c = 0; c < C_; c += 4) {
    h0 = fmaf(pool[c + 0], W1[(c + 0) * C_ + j], h0);
    h1 = fmaf(pool[c + 1], W1[(c + 1) * C_ + j], h1);
    h2 = fmaf(pool[c + 2], W1[(c + 2) * C_ + j], h2);
    h3 = fmaf(pool[c + 3], W1[(c + 3) * C_ + j], h3);
  }
  float h = ((h0 + h1) + (h2 + h3)) + b1[j];
  // BatchNorm (inference) + ReLU
  h = gamma[j] * (h - bn_mean[j]) * rsqrtf(bn_var[j] + 1e-3f) + beta[j];
  h = fmaxf(h, 0.f);

  // grouped 1x1 conv -> 2 logits, + gumbel; hard sample = argmax
  float z0 = fmaf(h, Wg[j * 2 + 0], bg[j * 2 + 0]) + gumbel[(b * C_ + j) * 2 + 0];
  float z1 = fmaf(h, Wg[j * 2 + 1], bg[j * 2 + 1]) + gumbel[(b * C_ + j) * 2 + 1];
  // argmax picks index 0 on ties -> gate = 1 iff z1 > z0 strictly
  float g = (z1 > z0) ? 1.0f : 0.0f;

  ws_gate[b * C_ + j] = g;
  out_gate[b * C_ + j] = g;
}

// ---------------- Kernel 3: x = inputs * gate[b,c] ----------------
// 8192 blocks x 256 threads; each thread handles 4 float4s at the same
// channel-group (one gate load reused 4x), 4 independent load->mul->store
// chains for memory-level parallelism. Nontemporal stores keep the
// L3-resident input from being evicted by the output stream.
__global__ __launch_bounds__(256) void apply_gate_kernel(
    const float* __restrict__ in, const float* __restrict__ ws_gate,
    float* __restrict__ out) {
  const vfloat4* in4 = (const vfloat4*)in;
  const vfloat4* g4 = (const vfloat4*)ws_gate;
  vfloat4* out4 = (vfloat4*)out;

  const int t = threadIdx.x;
  const int lane = t & 63;   // channel-group c4
  const int grp = t >> 6;    // 0..3

  // Block covers 1024 consecutive float4s = 16 positions x 64 channel-groups.
  long base = (long)blockIdx.x * 1024;
  long i0 = base + (long)grp * 256 + lane;  // then +64, +128, +192

  int b = (int)(base >> 18);  // 2^18 float4s per batch; constant per block
  vfloat4 g = g4[b * C4_ + lane];

  vfloat4 v0 = in4[i0];
  vfloat4 v1 = in4[i0 + 64];
  vfloat4 v2 = in4[i0 + 128];
  vfloat4 v3 = in4[i0 + 192];

  v0 *= g;
  v1 *= g;
  v2 *= g;
  v3 *= g;

  __builtin_nontemporal_store(v0, &out4[i0]);
  __builtin_nontemporal_store(v1, &out4[i0 + 64]);
  __builtin_nontemporal_store(v2, &out4[i0 + 128]);
  __builtin_nontemporal_store(v3, &out4[i0 + 192]);
}

extern "C" void kernel_launch(void* const* d_in, const int* in_sizes, int n_in,
                              void* d_out, int out_size, void* d_ws, size_t ws_size,
                              hipStream_t stream) {
  const float* inputs  = (const float*)d_in[0];
  const float* factor  = (const float*)d_in[1];
  const float* W1      = (const float*)d_in[2];
  const float* b1      = (const float*)d_in[3];
  const float* gamma   = (const float*)d_in[4];
  const float* beta    = (const float*)d_in[5];
  const float* bn_mean = (const float*)d_in[6];
  const float* bn_var  = (const float*)d_in[7];
  const float* Wg      = (const float*)d_in[8];
  const float* bg      = (const float*)d_in[9];
  const float* gumbel  = (const float*)d_in[10];

  float* out_x = (float*)d_out;                          // B*H*W*C floats
  float* out_gate = (float*)d_out + (long)B_ * HW_ * C_; // B*C floats

  // Workspace layout (floats):
  float* ws_sum  = (float*)d_ws;                   // B*NCHUNK*C = 262144
  float* ws_max  = ws_sum + B_ * NCHUNK * C_;      // 262144
  float* ws_gate = ws_max + B_ * NCHUNK * C_;      // B*C = 8192

  pool_partial_kernel<<<B_ * NCHUNK, 256, 0, stream>>>(inputs, ws_sum, ws_max);

  gate_kernel<<<B_, 256, 0, stream>>>(ws_sum, ws_max, factor, W1, b1, gamma,
                                      beta, bn_mean, bn_var, Wg, bg, gumbel,
                                      ws_gate, out_gate);

  const long n4 = (long)B_ * HW_ * C4_;  // 2^23 float4s
  apply_gate_kernel<<<(int)(n4 / 1024), 256, 0, stream>>>(inputs, ws_gate, out_x);
}